// Round 1
// baseline (156.700 us; speedup 1.0000x reference)
//
#include <hip/hip_runtime.h>

// RotationalConv2D: extract 5x5 patches, rotate each by its intensity-centroid
// angle (bilinear), then dot with W [F,5,5,C] and add bias.
// Shapes: in [4,128,128,16] f32, W [32,5,5,16], b [32], out [4,124,124,32] f32.

#define KS     5
#define TILE   16
#define TW     (TILE + KS - 1)     // 20
#define CPAD   20                  // padded channel stride (floats); 20*4B=80B, 16B-aligned
#define C_IN   16
#define F_OUT  32
#define FSPLIT 2
#define FPER   (F_OUT / FSPLIT)    // 16
#define H_IN   128
#define W_IN   128
#define HO     124
#define WO     124
#define NBATCH 4
#define EPSF   1e-7f
#define BLOCK  (TILE * TILE * FSPLIT)   // 512

__global__ __launch_bounds__(BLOCK) void rotconv_kernel(
    const float* __restrict__ in, const float* __restrict__ Wg,
    const float* __restrict__ bg, float* __restrict__ out)
{
    __shared__ float s_in[TW * TW * CPAD];      // 20*20*20 = 8000 floats = 32 KB
    __shared__ float s_int[TW * (TW + 1)];      // intensity, padded rows

    const int tid  = threadIdx.x;
    const int bx   = blockIdx.x, by = blockIdx.y, bimg = blockIdx.z;
    const int ox   = bx * TILE,  oy = by * TILE;

    // ---- stage input tile (20x20x16) into LDS, float4 over channels ----
    const float* inb = in + (size_t)bimg * (H_IN * W_IN * C_IN);
    for (int i = tid; i < TW * TW * (C_IN / 4); i += BLOCK) {
        int cv = i & 3;          // C_IN/4 == 4
        int p  = i >> 2;
        int x  = p % TW, y = p / TW;
        int gy = oy + y, gx = ox + x;
        float4 v = make_float4(0.f, 0.f, 0.f, 0.f);
        if (gy < H_IN && gx < W_IN)
            v = *(const float4*)(inb + ((size_t)(gy * W_IN + gx) * C_IN) + 4 * cv);
        *(float4*)(&s_in[p * CPAD + 4 * cv]) = v;
    }
    __syncthreads();

    // ---- intensity = channel sum per position ----
    for (int p = tid; p < TW * TW; p += BLOCK) {
        const float* sp = &s_in[p * CPAD];
        float s = 0.f;
        #pragma unroll
        for (int c = 0; c < C_IN; ++c) s += sp[c];
        int y = p / TW, x = p % TW;
        s_int[y * (TW + 1) + x] = s;
    }
    __syncthreads();

    // ---- per-pixel work ----
    const int lx = tid & (TILE - 1);
    const int ly = (tid >> 4) & (TILE - 1);
    const int fg = tid >> 8;              // 0 or 1: which half of F
    const int ho = oy + ly, wo = ox + lx;

    // centroid from intensity
    float tot = EPSF, cr = 0.f, cc = 0.f;
    #pragma unroll
    for (int dy = 0; dy < KS; ++dy) {
        #pragma unroll
        for (int dx = 0; dx < KS; ++dx) {
            float v = s_int[(ly + dy) * (TW + 1) + (lx + dx)];
            tot += v;
            cr  += v * (float)dy;
            cc  += v * (float)dx;
        }
    }
    cr /= tot;
    cc /= tot;

    float ang = atan2f(cr - 2.0f, cc - 2.0f + EPSF);
    float si, co;
    sincosf(ang, &si, &co);

    const float scl  = 1.0f / (1.0f + EPSF);
    float xoff = (4.0f - (co * 4.0f - si * 4.0f)) * 0.5f;
    float yoff = (4.0f - (si * 4.0f + co * 4.0f)) * 0.5f;

    float acc[FPER];
    const float* bb = bg + fg * FPER;
    #pragma unroll
    for (int f = 0; f < FPER; ++f) acc[f] = bb[f];   // uniform -> s_load

    const float* wbase = Wg + (size_t)fg * FPER * (KS * KS * C_IN);

    for (int ky = 0; ky < KS; ++ky) {
        for (int kx = 0; kx < KS; ++kx) {
            float sx = (co * (float)kx - si * (float)ky + xoff) * scl;
            float sy = (si * (float)kx + co * (float)ky + yoff) * scl;
            float fx0 = floorf(sx), fy0 = floorf(sy);
            float wx = sx - fx0, wy = sy - fy0;
            int x0 = (int)fx0, y0 = (int)fy0;
            int x1 = x0 + 1, y1 = y0 + 1;
            float vx0 = (x0 >= 0 && x0 < KS) ? 1.f : 0.f;
            float vx1 = (x1 >= 0 && x1 < KS) ? 1.f : 0.f;
            float vy0 = (y0 >= 0 && y0 < KS) ? 1.f : 0.f;
            float vy1 = (y1 >= 0 && y1 < KS) ? 1.f : 0.f;
            float w00 = (1.f - wx) * (1.f - wy) * vx0 * vy0;
            float w01 = wx * (1.f - wy) * vx1 * vy0;
            float w10 = (1.f - wx) * wy * vx0 * vy1;
            float w11 = wx * wy * vx1 * vy1;
            int cx0 = min(max(x0, 0), KS - 1), cx1 = min(max(x1, 0), KS - 1);
            int cy0 = min(max(y0, 0), KS - 1), cy1 = min(max(y1, 0), KS - 1);
            const float* p00 = &s_in[((ly + cy0) * TW + (lx + cx0)) * CPAD];
            const float* p01 = &s_in[((ly + cy0) * TW + (lx + cx1)) * CPAD];
            const float* p10 = &s_in[((ly + cy1) * TW + (lx + cx0)) * CPAD];
            const float* p11 = &s_in[((ly + cy1) * TW + (lx + cx1)) * CPAD];

            float4 rot[4];
            #pragma unroll
            for (int cv = 0; cv < 4; ++cv) {
                float4 a = *(const float4*)(p00 + 4 * cv);
                float4 b = *(const float4*)(p01 + 4 * cv);
                float4 c = *(const float4*)(p10 + 4 * cv);
                float4 d = *(const float4*)(p11 + 4 * cv);
                rot[cv].x = w00 * a.x + w01 * b.x + w10 * c.x + w11 * d.x;
                rot[cv].y = w00 * a.y + w01 * b.y + w10 * c.y + w11 * d.y;
                rot[cv].z = w00 * a.z + w01 * b.z + w10 * c.z + w11 * d.z;
                rot[cv].w = w00 * a.w + w01 * b.w + w10 * c.w + w11 * d.w;
            }

            // W reads are wave-uniform -> scalar loads on the SMEM pipe
            const float* wp = wbase + (ky * KS + kx) * C_IN;
            #pragma unroll
            for (int f = 0; f < FPER; ++f) {
                const float* wf = wp + f * (KS * KS * C_IN);
                float s = 0.f;
                #pragma unroll
                for (int cv = 0; cv < 4; ++cv) {
                    s += rot[cv].x * wf[4 * cv + 0];
                    s += rot[cv].y * wf[4 * cv + 1];
                    s += rot[cv].z * wf[4 * cv + 2];
                    s += rot[cv].w * wf[4 * cv + 3];
                }
                acc[f] += s;
            }
        }
    }

    if (ho < HO && wo < WO) {
        float* op = out + (((size_t)bimg * HO + ho) * WO + wo) * F_OUT + fg * FPER;
        #pragma unroll
        for (int f = 0; f < FPER; f += 4) {
            *(float4*)(op + f) = make_float4(acc[f], acc[f + 1], acc[f + 2], acc[f + 3]);
        }
    }
}

extern "C" void kernel_launch(void* const* d_in, const int* in_sizes, int n_in,
                              void* d_out, int out_size, void* d_ws, size_t ws_size,
                              hipStream_t stream) {
    const float* in = (const float*)d_in[0];
    const float* Wg = (const float*)d_in[1];
    const float* bg = (const float*)d_in[2];
    float* out      = (float*)d_out;
    dim3 grid((WO + TILE - 1) / TILE, (HO + TILE - 1) / TILE, NBATCH);
    rotconv_kernel<<<grid, dim3(BLOCK), 0, stream>>>(in, Wg, bg, out);
}

// Round 2
// 126.601 us; speedup vs baseline: 1.2377x; 1.2377x over previous
//
#include <hip/hip_runtime.h>

// RotationalConv2D: extract 5x5 patches, rotate each by its intensity-centroid
// angle (bilinear), then dot with W [F,5,5,C] and add bias.
// Shapes: in [4,128,128,16] f32, W [32,5,5,16], b [32], out [4,124,124,32] f32.
//
// R2: TILE 16->8, FSPLIT 2->4 (grid 256->1024 blocks, occupancy 22%->~50%);
//     W/b indexed via readfirstlane'd f-group -> uniform addresses -> s_load
//     (R1 emitted per-lane global_load_dwordx4 for every W element).

#define KS     5
#define TILE   8
#define TW     (TILE + KS - 1)     // 12
#define CPAD   20                  // padded channel stride (floats)
#define C_IN   16
#define F_OUT  32
#define FSPLIT 4
#define FPER   (F_OUT / FSPLIT)    // 8
#define H_IN   128
#define W_IN   128
#define HO     124
#define WO     124
#define NBATCH 4
#define EPSF   1e-7f
#define BLOCK  (TILE * TILE * FSPLIT)   // 256

__global__ __launch_bounds__(BLOCK) void rotconv_kernel(
    const float* __restrict__ in, const float* __restrict__ Wg,
    const float* __restrict__ bg, float* __restrict__ out)
{
    __shared__ float s_in[TW * TW * CPAD];      // 12*12*20 = 2880 floats = 11.5 KB
    __shared__ float s_int[TW * (TW + 1)];      // intensity, padded rows

    const int tid  = threadIdx.x;
    const int bx   = blockIdx.x, by = blockIdx.y, bimg = blockIdx.z;
    const int ox   = bx * TILE,  oy = by * TILE;

    // ---- stage input tile (12x12x16) into LDS, float4 over channels ----
    const float* inb = in + (size_t)bimg * (H_IN * W_IN * C_IN);
    for (int i = tid; i < TW * TW * (C_IN / 4); i += BLOCK) {
        int cv = i & 3;          // C_IN/4 == 4
        int p  = i >> 2;
        int x  = p % TW, y = p / TW;
        int gy = oy + y, gx = ox + x;
        float4 v = make_float4(0.f, 0.f, 0.f, 0.f);
        if (gy < H_IN && gx < W_IN)
            v = *(const float4*)(inb + ((size_t)(gy * W_IN + gx) * C_IN) + 4 * cv);
        *(float4*)(&s_in[p * CPAD + 4 * cv]) = v;
    }
    __syncthreads();

    // ---- intensity = channel sum per position ----
    for (int p = tid; p < TW * TW; p += BLOCK) {
        const float* sp = &s_in[p * CPAD];
        float s = 0.f;
        #pragma unroll
        for (int c = 0; c < C_IN; ++c) s += sp[c];
        int y = p / TW, x = p % TW;
        s_int[y * (TW + 1) + x] = s;
    }
    __syncthreads();

    // ---- per-pixel work ----
    const int lx = tid & (TILE - 1);
    const int ly = (tid >> 3) & (TILE - 1);
    // f-group: wave-uniform (waves are 64 consecutive tids). readfirstlane makes
    // it *provably* uniform so all W/b addresses go to the scalar (SMEM) pipe.
    const int fg = __builtin_amdgcn_readfirstlane(tid >> 6);
    const int ho = oy + ly, wo = ox + lx;

    // centroid from intensity
    float tot = EPSF, cr = 0.f, cc = 0.f;
    #pragma unroll
    for (int dy = 0; dy < KS; ++dy) {
        #pragma unroll
        for (int dx = 0; dx < KS; ++dx) {
            float v = s_int[(ly + dy) * (TW + 1) + (lx + dx)];
            tot += v;
            cr  += v * (float)dy;
            cc  += v * (float)dx;
        }
    }
    cr /= tot;
    cc /= tot;

    float ang = atan2f(cr - 2.0f, cc - 2.0f + EPSF);
    float si, co;
    sincosf(ang, &si, &co);

    const float scl  = 1.0f / (1.0f + EPSF);
    float xoff = (4.0f - (co * 4.0f - si * 4.0f)) * 0.5f;
    float yoff = (4.0f - (si * 4.0f + co * 4.0f)) * 0.5f;

    float acc[FPER];
    const float* bb = bg + fg * FPER;
    #pragma unroll
    for (int f = 0; f < FPER; ++f) acc[f] = bb[f];   // uniform -> s_load

    const float* wbase = Wg + (size_t)fg * FPER * (KS * KS * C_IN);

    for (int ky = 0; ky < KS; ++ky) {
        for (int kx = 0; kx < KS; ++kx) {
            float sx = (co * (float)kx - si * (float)ky + xoff) * scl;
            float sy = (si * (float)kx + co * (float)ky + yoff) * scl;
            float fx0 = floorf(sx), fy0 = floorf(sy);
            float wx = sx - fx0, wy = sy - fy0;
            int x0 = (int)fx0, y0 = (int)fy0;
            int x1 = x0 + 1, y1 = y0 + 1;
            float vx0 = (x0 >= 0 && x0 < KS) ? 1.f : 0.f;
            float vx1 = (x1 >= 0 && x1 < KS) ? 1.f : 0.f;
            float vy0 = (y0 >= 0 && y0 < KS) ? 1.f : 0.f;
            float vy1 = (y1 >= 0 && y1 < KS) ? 1.f : 0.f;
            float w00 = (1.f - wx) * (1.f - wy) * vx0 * vy0;
            float w01 = wx * (1.f - wy) * vx1 * vy0;
            float w10 = (1.f - wx) * wy * vx0 * vy1;
            float w11 = wx * wy * vx1 * vy1;
            int cx0 = min(max(x0, 0), KS - 1), cx1 = min(max(x1, 0), KS - 1);
            int cy0 = min(max(y0, 0), KS - 1), cy1 = min(max(y1, 0), KS - 1);
            const float* p00 = &s_in[((ly + cy0) * TW + (lx + cx0)) * CPAD];
            const float* p01 = &s_in[((ly + cy0) * TW + (lx + cx1)) * CPAD];
            const float* p10 = &s_in[((ly + cy1) * TW + (lx + cx0)) * CPAD];
            const float* p11 = &s_in[((ly + cy1) * TW + (lx + cx1)) * CPAD];

            float4 rot[4];
            #pragma unroll
            for (int cv = 0; cv < 4; ++cv) {
                float4 a = *(const float4*)(p00 + 4 * cv);
                float4 b = *(const float4*)(p01 + 4 * cv);
                float4 c = *(const float4*)(p10 + 4 * cv);
                float4 d = *(const float4*)(p11 + 4 * cv);
                rot[cv].x = w00 * a.x + w01 * b.x + w10 * c.x + w11 * d.x;
                rot[cv].y = w00 * a.y + w01 * b.y + w10 * c.y + w11 * d.y;
                rot[cv].z = w00 * a.z + w01 * b.z + w10 * c.z + w11 * d.z;
                rot[cv].w = w00 * a.w + w01 * b.w + w10 * c.w + w11 * d.w;
            }

            // W reads: uniform addresses (fg scalar, ky/kx/f compile-time) -> s_load
            const float* wp = wbase + (ky * KS + kx) * C_IN;
            #pragma unroll
            for (int f = 0; f < FPER; ++f) {
                const float* wf = wp + f * (KS * KS * C_IN);
                float s = 0.f;
                #pragma unroll
                for (int cv = 0; cv < 4; ++cv) {
                    s += rot[cv].x * wf[4 * cv + 0];
                    s += rot[cv].y * wf[4 * cv + 1];
                    s += rot[cv].z * wf[4 * cv + 2];
                    s += rot[cv].w * wf[4 * cv + 3];
                }
                acc[f] += s;
            }
        }
    }

    if (ho < HO && wo < WO) {
        float* op = out + (((size_t)bimg * HO + ho) * WO + wo) * F_OUT + fg * FPER;
        #pragma unroll
        for (int f = 0; f < FPER; f += 4) {
            *(float4*)(op + f) = make_float4(acc[f], acc[f + 1], acc[f + 2], acc[f + 3]);
        }
    }
}

extern "C" void kernel_launch(void* const* d_in, const int* in_sizes, int n_in,
                              void* d_out, int out_size, void* d_ws, size_t ws_size,
                              hipStream_t stream) {
    const float* in = (const float*)d_in[0];
    const float* Wg = (const float*)d_in[1];
    const float* bg = (const float*)d_in[2];
    float* out      = (float*)d_out;
    dim3 grid((WO + TILE - 1) / TILE, (HO + TILE - 1) / TILE, NBATCH);
    rotconv_kernel<<<grid, dim3(BLOCK), 0, stream>>>(in, Wg, bg, out);
}

// Round 3
// 76.147 us; speedup vs baseline: 2.0578x; 1.6626x over previous
//
#include <hip/hip_runtime.h>

// RotationalConv2D, MFMA restructure (R3).
// Phase per block (8x8 px, 256 thr / 4 waves):
//   stage 12x12x16 input tile -> LDS; intensity; per-pixel angle.
//   for each K-chunk (4 taps = 64 K of the 400-long rot vector):
//     wave q blends tap 4c+q for all 64 pixels (bf16) -> LDS A-panel [64 x 64+pad]
//     each wave: 2 M-tiles x 1 N-tile of mfma_f32_16x16x32_bf16, W from global (bf16 cvt)
// Removes the per-thread 3.2k-FMA dot (now MFMA) and the 4x FSPLIT blend duplication.

#define KS     5
#define TILE   8
#define NPIX   64
#define TW     (TILE + KS - 1)     // 12
#define CPAD   20                  // padded channel stride (floats)
#define C_IN   16
#define F_OUT  32
#define H_IN   128
#define W_IN   128
#define HO     124
#define WO     124
#define NBATCH 4
#define EPSF   1e-7f
#define BLOCK  256
#define NCHUNK 7                   // ceil(25 taps / 4)
#define AROW   72                  // 64 K + 8 pad (bf16 elems); 144 B row, 16B-aligned
#define KW     400                 // K = 25*16

typedef __attribute__((ext_vector_type(8))) short  short8;   // 8 bf16 (4 VGPRs)
typedef __attribute__((ext_vector_type(4))) float  floatx4;

static __device__ __forceinline__ short f2bf(float f) {
    union { float f; unsigned u; } v; v.f = f;
    unsigned r = v.u + 0x7fffu + ((v.u >> 16) & 1u);   // RNE
    return (short)(r >> 16);
}

__global__ __launch_bounds__(BLOCK) void rotconv_kernel(
    const float* __restrict__ in, const float* __restrict__ Wg,
    const float* __restrict__ bg, float* __restrict__ out)
{
    __shared__ float s_in[TW * TW * CPAD];      // 11.25 KB
    __shared__ float s_int[TW * (TW + 1)];      // 0.6 KB
    __shared__ short sA[NPIX * AROW];           // 9 KB

    const int tid  = threadIdx.x;
    const int bx = blockIdx.x, by = blockIdx.y, bimg = blockIdx.z;
    const int ox = bx * TILE, oy = by * TILE;

    // ---- stage input tile (12x12x16) ----
    const float* inb = in + (size_t)bimg * (H_IN * W_IN * C_IN);
    for (int i = tid; i < TW * TW * (C_IN / 4); i += BLOCK) {
        int cv = i & 3;
        int pp = i >> 2;
        int x = pp % TW, y = pp / TW;
        int gy = oy + y, gx = ox + x;
        float4 v = make_float4(0.f, 0.f, 0.f, 0.f);
        if (gy < H_IN && gx < W_IN)
            v = *(const float4*)(inb + ((size_t)(gy * W_IN + gx) * C_IN) + 4 * cv);
        *(float4*)(&s_in[pp * CPAD + 4 * cv]) = v;
    }
    __syncthreads();

    // ---- intensity = channel sum ----
    for (int pp = tid; pp < TW * TW; pp += BLOCK) {
        const float* sp = &s_in[pp * CPAD];
        float s = 0.f;
        #pragma unroll
        for (int c = 0; c < C_IN; ++c) s += sp[c];
        s_int[(pp / TW) * (TW + 1) + (pp % TW)] = s;
    }
    __syncthreads();

    const int p    = tid & 63;     // pixel index in 8x8 tile == lane
    const int wv   = tid >> 6;     // wave id 0..3
    const int lx   = p & 7, ly = p >> 3;
    const int col  = p & 15;       // MFMA lane&15
    const int quad = p >> 4;       // MFMA lane>>4

    // ---- per-pixel angle (redundant across the 4 waves; cheap) ----
    float tot = EPSF, cr = 0.f, cc = 0.f;
    #pragma unroll
    for (int dy = 0; dy < KS; ++dy)
        #pragma unroll
        for (int dx = 0; dx < KS; ++dx) {
            float v = s_int[(ly + dy) * (TW + 1) + (lx + dx)];
            tot += v; cr += v * (float)dy; cc += v * (float)dx;
        }
    cr /= tot; cc /= tot;
    float ang = atan2f(cr - 2.0f, cc - 2.0f + EPSF);
    float si, co;
    sincosf(ang, &si, &co);
    const float scl = 1.0f / (1.0f + EPSF);
    float xoff = (4.0f - (co * 4.0f - si * 4.0f)) * 0.5f;
    float yoff = (4.0f - (si * 4.0f + co * 4.0f)) * 0.5f;

    // ---- MFMA roles: wave -> (N-tile, two M-tiles) so B-loads aren't 4x duplicated ----
    const int nt  = wv >> 1;           // 0/1 : which 16 of F
    const int mt0 = (wv & 1) * 2;      // M-tiles mt0, mt0+1 (16 px each)

    floatx4 acc0, acc1;
    {
        float bv = bg[nt * 16 + col];  // bias pre-load into accumulator
        acc0 = (floatx4){bv, bv, bv, bv};
        acc1 = acc0;
    }

    for (int ch = 0; ch < NCHUNK; ++ch) {
        // ---- blend: wave wv computes tap t = 4ch+wv for its 64 pixels ----
        int t = 4 * ch + wv;
        short8 alo = {0,0,0,0,0,0,0,0}, ahi = {0,0,0,0,0,0,0,0};
        if (t < KS * KS) {                       // wave-uniform branch
            int ky = t / KS, kx = t - KS * ky;
            float sx = (co * (float)kx - si * (float)ky + xoff) * scl;
            float sy = (si * (float)kx + co * (float)ky + yoff) * scl;
            float fx0 = floorf(sx), fy0 = floorf(sy);
            float wx = sx - fx0, wy = sy - fy0;
            int x0 = (int)fx0, y0 = (int)fy0;
            int x1 = x0 + 1, y1 = y0 + 1;
            float vx0 = (x0 >= 0 && x0 < KS) ? 1.f : 0.f;
            float vx1 = (x1 >= 0 && x1 < KS) ? 1.f : 0.f;
            float vy0 = (y0 >= 0 && y0 < KS) ? 1.f : 0.f;
            float vy1 = (y1 >= 0 && y1 < KS) ? 1.f : 0.f;
            float w00 = (1.f - wx) * (1.f - wy) * vx0 * vy0;
            float w01 = wx * (1.f - wy) * vx1 * vy0;
            float w10 = (1.f - wx) * wy * vx0 * vy1;
            float w11 = wx * wy * vx1 * vy1;
            int cx0 = min(max(x0, 0), KS - 1), cx1 = min(max(x1, 0), KS - 1);
            int cy0 = min(max(y0, 0), KS - 1), cy1 = min(max(y1, 0), KS - 1);
            const float* p00 = &s_in[((ly + cy0) * TW + (lx + cx0)) * CPAD];
            const float* p01 = &s_in[((ly + cy0) * TW + (lx + cx1)) * CPAD];
            const float* p10 = &s_in[((ly + cy1) * TW + (lx + cx0)) * CPAD];
            const float* p11 = &s_in[((ly + cy1) * TW + (lx + cx1)) * CPAD];
            float r[16];
            #pragma unroll
            for (int cv = 0; cv < 4; ++cv) {
                float4 a = *(const float4*)(p00 + 4 * cv);
                float4 b = *(const float4*)(p01 + 4 * cv);
                float4 c = *(const float4*)(p10 + 4 * cv);
                float4 d = *(const float4*)(p11 + 4 * cv);
                r[4*cv+0] = w00 * a.x + w01 * b.x + w10 * c.x + w11 * d.x;
                r[4*cv+1] = w00 * a.y + w01 * b.y + w10 * c.y + w11 * d.y;
                r[4*cv+2] = w00 * a.z + w01 * b.z + w10 * c.z + w11 * d.z;
                r[4*cv+3] = w00 * a.w + w01 * b.w + w10 * c.w + w11 * d.w;
            }
            alo = (short8){f2bf(r[0]), f2bf(r[1]), f2bf(r[2]), f2bf(r[3]),
                           f2bf(r[4]), f2bf(r[5]), f2bf(r[6]), f2bf(r[7])};
            ahi = (short8){f2bf(r[8]),  f2bf(r[9]),  f2bf(r[10]), f2bf(r[11]),
                           f2bf(r[12]), f2bf(r[13]), f2bf(r[14]), f2bf(r[15])};
        }
        __syncthreads();                          // prev chunk's A fully consumed
        *(short8*)(&sA[p * AROW + wv * 16])     = alo;
        *(short8*)(&sA[p * AROW + wv * 16 + 8]) = ahi;
        __syncthreads();                          // A-panel ready

        // ---- MFMA over this 64-K chunk ----
        int nk = (ch == NCHUNK - 1) ? 1 : 2;      // last chunk: K 384..415 only
        for (int kk = 0; kk < nk; ++kk) {
            int kg = ch * 64 + kk * 32 + quad * 8;
            short8 bf = {0,0,0,0,0,0,0,0};
            if (kg + 8 <= KW) {                   // clamp: K>=400 rows are zero
                const float* wp = Wg + (size_t)(nt * 16 + col) * KW + kg;
                float4 a = *(const float4*)(wp);
                float4 b = *(const float4*)(wp + 4);
                bf = (short8){f2bf(a.x), f2bf(a.y), f2bf(a.z), f2bf(a.w),
                              f2bf(b.x), f2bf(b.y), f2bf(b.z), f2bf(b.w)};
            }
            short8 a0 = *(const short8*)(&sA[(16 * mt0 + col) * AROW + kk * 32 + quad * 8]);
            short8 a1 = *(const short8*)(&sA[(16 * mt0 + 16 + col) * AROW + kk * 32 + quad * 8]);
            acc0 = __builtin_amdgcn_mfma_f32_16x16x32_bf16(a0, bf, acc0, 0, 0, 0);
            acc1 = __builtin_amdgcn_mfma_f32_16x16x32_bf16(a1, bf, acc1, 0, 0, 0);
        }
    }

    // ---- epilogue: C/D layout col=lane&15 (f), row=quad*4+reg (pixel) ----
    #pragma unroll
    for (int r = 0; r < 4; ++r) {
        int pix0 = 16 * mt0 + quad * 4 + r;
        int ho = oy + (pix0 >> 3), wo = ox + (pix0 & 7);
        if (ho < HO && wo < WO)
            out[(((size_t)bimg * HO + ho) * WO + wo) * F_OUT + nt * 16 + col] = acc0[r];
        int pix1 = pix0 + 16;
        ho = oy + (pix1 >> 3); wo = ox + (pix1 & 7);
        if (ho < HO && wo < WO)
            out[(((size_t)bimg * HO + ho) * WO + wo) * F_OUT + nt * 16 + col] = acc1[r];
    }
}

extern "C" void kernel_launch(void* const* d_in, const int* in_sizes, int n_in,
                              void* d_out, int out_size, void* d_ws, size_t ws_size,
                              hipStream_t stream) {
    const float* in = (const float*)d_in[0];
    const float* Wg = (const float*)d_in[1];
    const float* bg = (const float*)d_in[2];
    float* out      = (float*)d_out;
    dim3 grid((WO + TILE - 1) / TILE, (HO + TILE - 1) / TILE, NBATCH);
    rotconv_kernel<<<grid, dim3(BLOCK), 0, stream>>>(in, Wg, bg, out);
}